// Round 1
// baseline (590.353 us; speedup 1.0000x reference)
//
#include <hip/hip_runtime.h>
#include <math.h>

// out = h - softplus(log_gamma) * ((topk_gate(s) * (h @ V^T)) @ V)
// Only top_k=64 columns of s survive per row, so we never form the dense
// [2048, 32768] projection: per row, find exact top-64 of s, then
// out = h - gamma * sum_j s_j * (h . V[j]) * V[j].

constexpr int NSEEN  = 32768;
constexpr int HIDDEN = 768;
constexpr int NBINS  = 2048;
constexpr int SEG    = NBINS / 256;   // bins per thread in partial sums
constexpr int CAP    = 2048;          // candidate buffer entries
constexpr int KMAX   = 64;

// order-preserving bit map for arbitrary floats (fallback path)
__device__ inline unsigned int ordkey(float x) {
    unsigned int u = __float_as_uint(x);
    return (u & 0x80000000u) ? ~u : (u | 0x80000000u);
}
__device__ inline float ordkey_inv(unsigned int o) {
    unsigned int u = (o & 0x80000000u) ? (o ^ 0x80000000u) : ~o;
    return __uint_as_float(u);
}

// bucket index under the current mode; -1 means "below all candidate bins"
__device__ inline int bucket_of(float x, int mode, float lo, float scale) {
    if (mode == 0) {
        if (x < lo) return -1;
        int b = (int)((x - lo) * scale);
        return (b > NBINS - 1) ? (NBINS - 1) : b;
    } else {
        return (int)(ordkey(x) >> 21);   // top 11 bits -> 2048 bins, fully monotone
    }
}

__global__ __launch_bounds__(256)
void stl_topk_kernel(const float* __restrict__ H,
                     const float* __restrict__ S,
                     const float* __restrict__ V,
                     const float* __restrict__ LG,
                     const int*   __restrict__ KP,
                     float* __restrict__ OUT)
{
    const int row  = blockIdx.x;
    const int tid  = threadIdx.x;
    const int lane = tid & 63;
    const int wav  = tid >> 6;

    __shared__ unsigned int hist[NBINS];          // 8 KB
    __shared__ unsigned long long cand[CAP];      // 16 KB
    __shared__ float hlds[HIDDEN];                // 3 KB
    __shared__ unsigned int suff[256];            // 1 KB
    __shared__ float coef[KMAX];
    __shared__ float selval[KMAX];
    __shared__ unsigned int selidx[KMAX];
    __shared__ unsigned int scount;
    __shared__ int sbin;
    __shared__ int sseg;

    int k = KP[0];
    if (k < 1)    k = 1;
    if (k > KMAX) k = KMAX;

    const float lgv   = LG[0];
    const float gamma = (lgv > 20.f) ? lgv : log1pf(expf(lgv));

    // stage h row into LDS
    const float* hrow = H + (size_t)row * HIDDEN;
    for (int c = tid; c < HIDDEN; c += 256) hlds[c] = hrow[c];

    const float4* srow4 = (const float4*)(S + (size_t)row * NSEEN);

    // ---- phase 1: exact threshold-bin selection --------------------------
    // mode 0: linear bins over [0.98, 1.0) (covers top-64 of U[0,1] data,
    //         ~2% of elements hit the LDS atomics). mode 1: order-bits over
    //         the full float range (always succeeds).
    int   mode  = 0;
    float lo    = 0.98f;
    float scale = (float)NBINS / 0.02f;
    int   B     = 0;

    for (int attempt = 0; attempt < 2; ++attempt) {
        for (int b = tid; b < NBINS; b += 256) hist[b] = 0;
        __syncthreads();

        for (int i = tid; i < NSEEN / 4; i += 256) {
            float4 v = srow4[i];
            float xs[4] = {v.x, v.y, v.z, v.w};
            #pragma unroll
            for (int c = 0; c < 4; ++c) {
                int b = bucket_of(xs[c], mode, lo, scale);
                if (b >= 0) atomicAdd(&hist[b], 1u);
            }
        }
        __syncthreads();

        // per-thread partial over SEG bins, then inclusive suffix scan
        unsigned int ps = 0;
        #pragma unroll
        for (int u = 0; u < SEG; ++u) ps += hist[tid * SEG + u];
        suff[tid] = ps;
        __syncthreads();
        for (int d = 1; d < 256; d <<= 1) {
            unsigned int add = (tid + d < 256) ? suff[tid + d] : 0u;
            __syncthreads();
            suff[tid] += add;
            __syncthreads();
        }

        unsigned int total = suff[0];
        if (total >= (unsigned)k) {
            // largest segment t with suffix >= k (unique since suff is non-increasing)
            if (suff[tid] >= (unsigned)k && (tid == 255 || suff[tid + 1] < (unsigned)k))
                sseg = tid;
            __syncthreads();
            if (tid == 0) {
                int t = sseg;
                unsigned int running = (t < 255) ? suff[t + 1] : 0u;
                int b = t * SEG + SEG - 1;
                for (; b > t * SEG; --b) {
                    running += hist[b];
                    if (running >= (unsigned)k) break;
                }
                if (running < (unsigned)k) { /* last bin of segment */ running += hist[b]; }
                sbin   = b;
                scount = 0;
            }
            __syncthreads();
            B = sbin;
            break;
        }
        // fallback: full-range order-bits histogram
        mode = 1;
        __syncthreads();
    }

    // ---- phase 2: collect candidates (all elements in bins >= B) ---------
    for (int i = tid; i < NSEEN / 4; i += 256) {
        float4 v = srow4[i];
        float xs[4] = {v.x, v.y, v.z, v.w};
        #pragma unroll
        for (int c = 0; c < 4; ++c) {
            float x = xs[c];
            int b = bucket_of(x, mode, lo, scale);
            if (b >= B) {
                unsigned int pos = atomicAdd(&scount, 1u);
                if (pos < CAP) {
                    unsigned int idx = (unsigned int)(4 * i + c);
                    cand[pos] = ((unsigned long long)ordkey(x) << 32) | (unsigned int)(~idx);
                }
            }
        }
    }
    __syncthreads();

    unsigned int C = scount;
    if (C > CAP) C = CAP;

    // ---- phase 3: exact k-way argmax extraction (wave 0) ------------------
    // key = (ordkey(value) << 32) | ~index : descending value, ties -> lower
    // index first (matches jax.lax.top_k).
    if (wav == 0) {
        for (int j = 0; j < k; ++j) {
            unsigned long long best = 0ULL;
            int bslot = 0;
            for (int p = lane; p < (int)C; p += 64) {
                unsigned long long key = cand[p];
                if (key > best) { best = key; bslot = p; }
            }
            #pragma unroll
            for (int d = 32; d >= 1; d >>= 1) {
                unsigned long long ok = __shfl_xor(best, d, 64);
                int os = __shfl_xor(bslot, d, 64);
                if (ok > best) { best = ok; bslot = os; }
            }
            if (lane == 0) {
                selval[j] = ordkey_inv((unsigned int)(best >> 32));
                selidx[j] = ~(unsigned int)(best & 0xFFFFFFFFu);
            }
            cand[bslot] = 0ULL;   // all lanes, same addr/value; DS ops in-order per wave
        }
    }
    __syncthreads();

    // ---- phase 4: dots  d_j = h . V[j]  (wave w handles j = w, w+4, ...) --
    for (int j = wav; j < k; j += 4) {
        const float* vrow = V + (size_t)selidx[j] * HIDDEN;
        float p = 0.f;
        #pragma unroll
        for (int t = 0; t < HIDDEN / 64; ++t) {
            int c = lane + 64 * t;
            p += hlds[c] * vrow[c];
        }
        #pragma unroll
        for (int d = 1; d < 64; d <<= 1) p += __shfl_xor(p, d, 64);
        if (lane == 0) coef[j] = selval[j] * p;
    }
    __syncthreads();

    // ---- phase 5: out = h - gamma * sum_j coef_j * V[j] -------------------
    float acc0 = 0.f, acc1 = 0.f, acc2 = 0.f;
    for (int j = 0; j < k; ++j) {
        const float cf = coef[j];
        const float* vrow = V + (size_t)selidx[j] * HIDDEN;
        acc0 += cf * vrow[tid];
        acc1 += cf * vrow[tid + 256];
        acc2 += cf * vrow[tid + 512];
    }
    float* orow = OUT + (size_t)row * HIDDEN;
    orow[tid]       = hlds[tid]       - gamma * acc0;
    orow[tid + 256] = hlds[tid + 256] - gamma * acc1;
    orow[tid + 512] = hlds[tid + 512] - gamma * acc2;
}

extern "C" void kernel_launch(void* const* d_in, const int* in_sizes, int n_in,
                              void* d_out, int out_size, void* d_ws, size_t ws_size,
                              hipStream_t stream) {
    const float* H  = (const float*)d_in[0];
    const float* S  = (const float*)d_in[1];
    const float* V  = (const float*)d_in[2];
    const float* LG = (const float*)d_in[3];
    const int*   KP = (const int*)d_in[4];
    float* OUT = (float*)d_out;

    const int rows = in_sizes[1] / NSEEN;   // 2048
    stl_topk_kernel<<<dim3(rows), dim3(256), 0, stream>>>(H, S, V, LG, KP, OUT);
}

// Round 2
// 511.874 us; speedup vs baseline: 1.1533x; 1.1533x over previous
//
#include <hip/hip_runtime.h>
#include <math.h>

// out = h - softplus(log_gamma) * ((topk_gate(s) * (h @ V^T)) @ V)
// Per row: exact top-64 of s, then out = h - gamma * sum_j s_j (h.V[j]) V[j].
// Single pass over S: histogram (>= LO) + wave-aggregated candidate collection.
// Selection: all candidates in bins > B are in the set (order-invariant sum);
// only k - cnt_gt elements (typically 1) need exact key extraction from bin B.

constexpr int   NSEEN  = 32768;
constexpr int   HIDDEN = 768;
constexpr int   NBINS  = 1024;
constexpr int   SEG    = NBINS / 256;   // 4
constexpr int   CAP    = 1024;          // candidate buffer (expected ~655 at LO=0.98)
constexpr int   KMAX   = 64;
constexpr float LO     = 0.98f;

__device__ inline unsigned ordkey(float x) {
    unsigned u = __float_as_uint(x);
    return (u & 0x80000000u) ? ~u : (u | 0x80000000u);
}
__device__ inline float ordkey_inv(unsigned o) {
    unsigned u = (o & 0x80000000u) ? (o ^ 0x80000000u) : ~o;
    return __uint_as_float(u);
}
__device__ inline int bucket_of(float x, int mode, float scale) {
    if (mode == 0) {
        if (x < LO) return -1;
        int b = (int)((x - LO) * scale);
        return (b > NBINS - 1) ? (NBINS - 1) : b;
    }
    return (int)(ordkey(x) >> 22);      // 1024 full-range monotone bins
}

// wave-aggregated LDS push: 1 atomic per wave per call
__device__ inline void wave_push(bool pred, unsigned long long key, int lane,
                                 unsigned* counter, unsigned long long* buf, int cap) {
    unsigned long long m = __ballot(pred);
    if (m) {
        int leader = __ffsll((unsigned long long)m) - 1;
        unsigned base = 0;
        if (lane == leader) base = atomicAdd(counter, (unsigned)__popcll(m));
        base = __shfl(base, leader, 64);
        if (pred) {
            unsigned pos = base + (unsigned)__popcll(m & ((1ULL << lane) - 1ULL));
            if (pos < (unsigned)cap) buf[pos] = key;
        }
    }
}

__global__ __launch_bounds__(256)
void stl_topk_kernel(const float* __restrict__ H,
                     const float* __restrict__ S,
                     const float* __restrict__ V,
                     const float* __restrict__ LG,
                     const int*   __restrict__ KP,
                     float* __restrict__ OUT)
{
    const int row  = blockIdx.x;
    const int tid  = threadIdx.x;
    const int lane = tid & 63;
    const int wav  = tid >> 6;

    __shared__ unsigned hist[NBINS];                     // 4 KB
    __shared__ unsigned long long cand[CAP];             // 8 KB
    __shared__ __align__(16) float hlds[HIDDEN];         // 3 KB
    __shared__ unsigned suff[256];                       // 1 KB
    __shared__ unsigned long long selkey[KMAX];
    __shared__ float selval[KMAX];
    __shared__ unsigned selidx[KMAX];
    __shared__ float coef[KMAX];
    __shared__ unsigned scount, ssel;
    __shared__ int sseg, sbin;
    __shared__ unsigned scnt_gt;

    int k = KP[0];
    if (k < 1)    k = 1;
    if (k > KMAX) k = KMAX;

    const float lgv   = LG[0];
    const float gamma = (lgv > 20.f) ? lgv : log1pf(expf(lgv));
    const float scale = (float)NBINS / (1.0f - LO);

    // stage h row
    const float* hrow = H + (size_t)row * HIDDEN;
    for (int c = tid; c < HIDDEN; c += 256) hlds[c] = hrow[c];

    const float4* srow4 = (const float4*)(S + (size_t)row * NSEEN);

    // ---- single pass over S: histogram (>=LO) + collect candidates --------
    for (int b = tid; b < NBINS; b += 256) hist[b] = 0;
    if (tid == 0) scount = 0;
    __syncthreads();

    int mode = 0;
    for (int i = tid; i < NSEEN / 4; i += 256) {
        float4 v = srow4[i];
        float xs[4] = {v.x, v.y, v.z, v.w};
        #pragma unroll
        for (int c = 0; c < 4; ++c) {
            float x = xs[c];
            bool pred = (x >= LO);
            if (pred) {
                int b = bucket_of(x, 0, scale);
                atomicAdd(&hist[b], 1u);
            }
            unsigned idx = (unsigned)(4 * i + c);
            unsigned long long key =
                ((unsigned long long)ordkey(x) << 32) | (unsigned)(~idx);
            wave_push(pred, key, lane, &scount, cand, CAP);
        }
    }
    __syncthreads();

    unsigned C = scount;

    // ---- fallback (never on this data): full-range order-bit histogram ----
    if (C < (unsigned)k || C > (unsigned)CAP) {
        mode = 1;
        for (int b = tid; b < NBINS; b += 256) hist[b] = 0;
        __syncthreads();
        for (int i = tid; i < NSEEN / 4; i += 256) {
            float4 v = srow4[i];
            float xs[4] = {v.x, v.y, v.z, v.w};
            #pragma unroll
            for (int c = 0; c < 4; ++c)
                atomicAdd(&hist[bucket_of(xs[c], 1, scale)], 1u);
        }
        __syncthreads();
    }

    // ---- scan: per-thread partials + inclusive suffix scan → bin B --------
    unsigned ps = 0;
    #pragma unroll
    for (int u = 0; u < SEG; ++u) ps += hist[tid * SEG + u];
    suff[tid] = ps;
    __syncthreads();
    for (int d = 1; d < 256; d <<= 1) {
        unsigned add = (tid + d < 256) ? suff[tid + d] : 0u;
        __syncthreads();
        suff[tid] += add;
        __syncthreads();
    }
    if (suff[tid] >= (unsigned)k && (tid == 255 || suff[tid + 1] < (unsigned)k))
        sseg = tid;
    __syncthreads();
    if (tid == 0) {
        int t = sseg;
        unsigned running = (t < 255) ? suff[t + 1] : 0u;
        int b = t * SEG + SEG - 1;
        for (;;) {
            running += hist[b];
            if (running >= (unsigned)k || b == t * SEG) break;
            --b;
        }
        sbin    = b;
        scnt_gt = running - hist[b];   // count in bins strictly > B (< k)
        ssel    = 0;
    }
    __syncthreads();

    const int B = sbin;
    const unsigned cnt_gt = scnt_gt;

    // ---- fallback collection: gather bins >= B from S ---------------------
    if (mode == 1) {
        if (tid == 0) scount = 0;
        __syncthreads();
        for (int i = tid; i < NSEEN / 4; i += 256) {
            float4 v = srow4[i];
            float xs[4] = {v.x, v.y, v.z, v.w};
            #pragma unroll
            for (int c = 0; c < 4; ++c) {
                float x = xs[c];
                bool pred = (bucket_of(x, 1, scale) >= B);
                unsigned idx = (unsigned)(4 * i + c);
                unsigned long long key =
                    ((unsigned long long)ordkey(x) << 32) | (unsigned)(~idx);
                wave_push(pred, key, lane, &scount, cand, CAP);
            }
        }
        __syncthreads();
        C = scount < (unsigned)CAP ? scount : (unsigned)CAP;
    }

    // ---- select: bins > B go straight in (set membership is all we need) --
    for (int p = tid; p < (int)C; p += 256) {
        unsigned long long key = cand[p];
        float val = ordkey_inv((unsigned)(key >> 32));
        bool pred = (bucket_of(val, mode, scale) > B);
        wave_push(pred, key, lane, &ssel, selkey, KMAX);
    }
    __syncthreads();

    // ---- remainder: exact key-ordered extraction from bin B (usually 1) ---
    if (wav == 0) {
        const int r = k - (int)cnt_gt;
        for (int it = 0; it < r; ++it) {
            unsigned long long best = 0ULL;
            int bslot = -1;
            for (int p = lane; p < (int)C; p += 64) {
                unsigned long long key = cand[p];
                if (key) {
                    float val = ordkey_inv((unsigned)(key >> 32));
                    if (bucket_of(val, mode, scale) == B && key > best) {
                        best = key; bslot = p;
                    }
                }
            }
            #pragma unroll
            for (int d = 32; d >= 1; d >>= 1) {
                unsigned long long ok = __shfl_xor(best, d, 64);
                int os = __shfl_xor(bslot, d, 64);
                if (ok > best) { best = ok; bslot = os; }
            }
            if (lane == 0) {
                selkey[cnt_gt + it] = best;
                cand[bslot] = 0ULL;
            }
        }
    }
    __syncthreads();

    // unpack selected keys
    if (tid < k) {
        unsigned long long key = selkey[tid];
        selval[tid] = ordkey_inv((unsigned)(key >> 32));
        selidx[tid] = ~(unsigned)(key & 0xFFFFFFFFu);
    }
    __syncthreads();

    // ---- dots: d_j = h . V[j], wave w handles j = w, w+4, ... -------------
    const float4* hl4 = (const float4*)hlds;
    for (int j = wav; j < k; j += 4) {
        const float4* vr4 = (const float4*)(V + (size_t)selidx[j] * HIDDEN);
        float p = 0.f;
        #pragma unroll
        for (int t = 0; t < HIDDEN / 256; ++t) {
            float4 a  = vr4[lane + 64 * t];
            float4 hq = hl4[lane + 64 * t];
            p += a.x * hq.x + a.y * hq.y + a.z * hq.z + a.w * hq.w;
        }
        #pragma unroll
        for (int d = 1; d < 64; d <<= 1) p += __shfl_xor(p, d, 64);
        if (lane == 0) coef[j] = selval[j] * p;
    }
    __syncthreads();

    // ---- out = h - gamma * sum_j coef_j * V[j] ----------------------------
    float acc0 = 0.f, acc1 = 0.f, acc2 = 0.f;
    for (int j = 0; j < k; ++j) {
        const float cf = coef[j];
        const float* vrow = V + (size_t)selidx[j] * HIDDEN;
        acc0 += cf * vrow[tid];
        acc1 += cf * vrow[tid + 256];
        acc2 += cf * vrow[tid + 512];
    }
    float* orow = OUT + (size_t)row * HIDDEN;
    orow[tid]       = hlds[tid]       - gamma * acc0;
    orow[tid + 256] = hlds[tid + 256] - gamma * acc1;
    orow[tid + 512] = hlds[tid + 512] - gamma * acc2;
}

extern "C" void kernel_launch(void* const* d_in, const int* in_sizes, int n_in,
                              void* d_out, int out_size, void* d_ws, size_t ws_size,
                              hipStream_t stream) {
    const float* H  = (const float*)d_in[0];
    const float* S  = (const float*)d_in[1];
    const float* V  = (const float*)d_in[2];
    const float* LG = (const float*)d_in[3];
    const int*   KP = (const int*)d_in[4];
    float* OUT = (float*)d_out;

    const int rows = in_sizes[1] / NSEEN;   // 2048
    stl_topk_kernel<<<dim3(rows), dim3(256), 0, stream>>>(H, S, V, LG, KP, OUT);
}